// Round 6
// baseline (670.305 us; speedup 1.0000x reference)
//
#include <hip/hip_runtime.h>
#include <hip/hip_bf16.h>

using bf16 = __hip_bfloat16;
typedef short short8  __attribute__((ext_vector_type(8)));   // 8 bf16 (4 VGPRs) MFMA frag
typedef short short4v __attribute__((ext_vector_type(4)));
typedef float f32x4   __attribute__((ext_vector_type(4)));   // MFMA accumulator
typedef unsigned int  uint;
typedef uint uint4v   __attribute__((ext_vector_type(4)));

static __device__ __forceinline__ bf16  f2b(float v){ return __float2bfloat16(v); }
static __device__ __forceinline__ float s2f(short s){ return __bfloat162float(__builtin_bit_cast(bf16, s)); }
static __device__ __forceinline__ short f2s(float f){ return __builtin_bit_cast(short, __float2bfloat16(f)); }
static __device__ __forceinline__ uint pk2(float lo, float hi){
  return (uint)(unsigned short)f2s(lo) | ((uint)(unsigned short)f2s(hi) << 16);
}

// fallback path: load 8 consecutive fp32 weights -> bf16x8 MFMA fragment
static __device__ __forceinline__ short8 ldw8(const float* __restrict__ p){
  const float4 u = *(const float4*)(p);
  const float4 v = *(const float4*)(p + 4);
  short8 r;
  r[0]=f2s(u.x); r[1]=f2s(u.y); r[2]=f2s(u.z); r[3]=f2s(u.w);
  r[4]=f2s(v.x); r[5]=f2s(v.y); r[6]=f2s(v.z); r[7]=f2s(v.w);
  return r;
}

#define MFMA16(a,b,c) __builtin_amdgcn_mfma_f32_16x16x32_bf16((a),(b),(c),0,0,0)

constexpr int TPB = 256;
constexpr float EPS = 1e-5f;
constexpr float QSC = 0.17677669529663687f;   // 32^-0.5

// ---- d_ws layout: pre-converted bf16 weights + dense rel-pos bias table
constexpr int WQ_OFF  = 0;        // qkvw  288x96 bf16 (q rows pre-scaled by QSC)
constexpr int WPJ_OFF = 27648;    // projw  96x96
constexpr int WF1_OFF = 36864;    // fc1w  192x96
constexpr int WF2_OFF = 55296;    // fc2w  96x192
constexpr int WTOT    = 73728;    // total bf16 weight elements
constexpr int BTAB_BYTE_OFF = 147456;          // fp32 [3][64][64]  btab[h][q][k]
constexpr size_t WS_NEEDED = 147456 + 49152;   // 196,608 B

// ---- LDS: TWO windows/block, two 24,576 B regions, time-shared. 49,152 B -> 3 blocks/CU.
//  A: s_a [128][192B] (x/LN1) -> {q[128][64B] @0, k[128][64B] @8192, vt[2][32][128B] @16384}
//     -> LN2-out [128][192B] -> s_at [96][256B]
//  B: s_ao [128][192B] (attn out) -> s_h half-buffer [128][192B]
constexpr int A_OFF = 0;
constexpr int B_OFF = 24576;
constexpr int SMEM_BYTES = 49152;   // *3 = 147,456 <= 163,840

__global__ void init_ws_kernel(
    const float* __restrict__ qkvw, const float* __restrict__ projw,
    const float* __restrict__ fc1w, const float* __restrict__ fc2w,
    const float* __restrict__ rpb,
    bf16* __restrict__ wbf, float* __restrict__ btab)
{
  const int i = blockIdx.x * 256 + threadIdx.x;
  if (i < WTOT){
    float v;
    if (i < WPJ_OFF)      v = qkvw[i];
    else if (i < WF1_OFF) v = projw[i - WPJ_OFF];
    else if (i < WF2_OFF) v = fc1w[i - WF1_OFF];
    else                  v = fc2w[i - WF2_OFF];
    if (i < 9216) v *= QSC;          // q-section rows 0..95: fold 1/sqrt(d)
    wbf[i] = f2b(v);
  }
  if (i < 3*64*64){
    const int h   = i >> 12;
    const int row = (i >> 6) & 63;   // q
    const int col = i & 63;          // k
    const int rel = ((row>>3) - (col>>3) + 7)*15 + ((row&7) - (col&7) + 7);
    btab[i] = rpb[rel*3 + h];
  }
}

template<bool PRE>
__global__ __launch_bounds__(TPB, 3) void swin_block_kernel(
    const float* __restrict__ x,
    const float* __restrict__ qkvw,  const float* __restrict__ qkvb,
    const float* __restrict__ projw, const float* __restrict__ projb,
    const float* __restrict__ rpb,
    const float* __restrict__ n1g,   const float* __restrict__ n1b,
    const float* __restrict__ n2g,   const float* __restrict__ n2b,
    const float* __restrict__ fc1w,  const float* __restrict__ fc1b,
    const float* __restrict__ fc2w,  const float* __restrict__ fc2b,
    float* __restrict__ out,
    const bf16* __restrict__ wbf,    const float* __restrict__ btab)
{
  __shared__ alignas(16) unsigned char smem[SMEM_BYTES];
  char* s_a  = (char*)(smem + A_OFF);            // [128][192B] (x/LN1; later LN2-out)
  char* s_q  = (char*)(smem + A_OFF);            // [128][64B]
  char* s_k  = (char*)(smem + A_OFF + 8192);     // [128][64B]
  char* s_vt = (char*)(smem + A_OFF + 16384);    // [2][32][128B]  V^T: [d][token]
  char* s_at = (char*)(smem + A_OFF);            // [96][256B]  ([c][token], fc2 out)
  char* s_ao = (char*)(smem + B_OFF);            // [128][192B] (attn out; wave-private rows)
  char* s_h  = (char*)(smem + B_OFF);            // [128][192B] (fc1 half out; wave-private rows)

  const bf16* wQ  = wbf + WQ_OFF;
  const bf16* wP  = wbf + WPJ_OFF;
  const bf16* wF1 = wbf + WF1_OFF;
  const bf16* wF2 = wbf + WF2_OFF;

  const int tid  = threadIdx.x;
  const int lane = tid & 63;
  const int wid  = tid >> 6;
  const int quad = lane >> 4;
  const int l15  = lane & 15;
  const int m0   = wid * 16;       // wave's m-tile rows within a window
  const int row0 = m0 + quad * 4;  // C/D frag rows (within window)

  // grid 4096: 8 batch x 32 wh x 16 window-pairs (2 adjacent windows along W)
  const int blk = blockIdx.x;
  const int b    = blk >> 9;
  const int wh   = (blk >> 4) & 31;
  const int wcol = blk & 15;
  const size_t base = ((size_t)b * 96) * 65536 + (size_t)wh * 2048 + (size_t)wcol * 16;
  // element (c, i, j) at base + c*65536 + i*256 + j ; j in [0,16): win = j>>3, token = i*8 + (j&7)

  // ---------------- load x (float4) -> token-major bf16 in s_a ----
  #pragma unroll
  for (int it = 0; it < 12; it++){
    const int idx4 = it*256 + tid;
    const int c = idx4 >> 5, r = idx4 & 31;
    const int irow = r >> 2, j0 = (r & 3) * 4;
    const float4 xv = *(const float4*)(x + base + (size_t)c*65536 + irow*256 + j0);
    const int srow = (j0 >> 3)*64 + irow*8 + (j0 & 7);
    *(bf16*)(s_a + (srow+0)*192 + c*2) = f2b(xv.x);
    *(bf16*)(s_a + (srow+1)*192 + c*2) = f2b(xv.y);
    *(bf16*)(s_a + (srow+2)*192 + c*2) = f2b(xv.z);
    *(bf16*)(s_a + (srow+3)*192 + c*2) = f2b(xv.w);
  }
  __syncthreads();   // (1) x-scatter is cross-wave

  // ---------------- LN1: 4 threads/row, 2 windows, wave-private rows ----
  {
    const int rr = tid >> 2, s = tid & 3;
    const int cb = s*24;               // 24 channels per thread; byte off 48s (16B-aligned)
    float gv[24], bb[24];
    #pragma unroll
    for (int u = 0; u < 6; u++){
      const float4 g4 = *(const float4*)(n1g + cb + u*4);
      const float4 b4 = *(const float4*)(n1b + cb + u*4);
      gv[u*4+0]=g4.x; gv[u*4+1]=g4.y; gv[u*4+2]=g4.z; gv[u*4+3]=g4.w;
      bb[u*4+0]=b4.x; bb[u*4+1]=b4.y; bb[u*4+2]=b4.z; bb[u*4+3]=b4.w;
    }
    #pragma unroll
    for (int wv = 0; wv < 2; wv++){
      char* row = s_a + (wv*64 + rr)*192 + cb*2;
      float vals[24];
      float sum = 0.f, sq = 0.f;
      #pragma unroll
      for (int u = 0; u < 3; u++){
        short8 v8 = *(const short8*)(row + u*16);
        #pragma unroll
        for (int j = 0; j < 8; j++){ float f = s2f(v8[j]); vals[u*8+j] = f; sum += f; sq += f*f; }
      }
      sum += __shfl_xor(sum, 1); sum += __shfl_xor(sum, 2);
      sq  += __shfl_xor(sq , 1); sq  += __shfl_xor(sq , 2);
      const float mu  = sum * (1.f/96.f);
      const float inv = rsqrtf(fmaxf(sq*(1.f/96.f) - mu*mu, 0.f) + EPS);
      #pragma unroll
      for (int u = 0; u < 3; u++){
        short8 o8;
        #pragma unroll
        for (int j = 0; j < 8; j++)
          o8[j] = f2s((vals[u*8+j] - mu) * inv * gv[u*8+j] + bb[u*8+j]);
        *(short8*)(row + u*16) = o8;
      }
    }
  }

  const f32x4 zac = {0.f, 0.f, 0.f, 0.f};

  // A-fragments of LN1(x) for both windows (own-wave rows; s_a then dead)
  short8 A0[2], A1[2], A2[2];
  #pragma unroll
  for (int wv = 0; wv < 2; wv++){
    const char* ap = s_a + (wv*64 + m0 + l15)*192 + quad*16;
    A0[wv] = *(const short8*)(ap);
    A1[wv] = *(const short8*)(ap + 64);
    A2[wv] = *(const short8*)(ap + 128);
  }
  __syncthreads();   // (2) all waves hoisted before q/k/vt overwrite A

  // ---------------- attention: head at a time; 2 barriers/head ----
  for (int h = 0; h < 3; h++){
    // ---- qkv_h : shared W-fragments serve both windows
    #pragma unroll
    for (int nt = 0; nt < 6; nt++){
      const int sect = nt >> 1;                 // 0=q 1=k 2=v
      const int d = (nt & 1)*16 + l15;          // 0..31 within head
      const int wrow = sect*96 + h*32 + d;      // row of qkv_w (288x96)
      short8 w0, w1, w2;
      if constexpr (PRE){
        const bf16* wp = wQ + wrow*96 + quad*8;
        w0 = *(const short8*)(wp);
        w1 = *(const short8*)(wp + 32);
        w2 = *(const short8*)(wp + 64);
      } else {
        const float* wp = qkvw + wrow*96 + quad*8;
        w0 = ldw8(wp); w1 = ldw8(wp + 32); w2 = ldw8(wp + 64);
      }
      float bias = qkvb[wrow];
      if (PRE && sect == 0) bias *= QSC;        // match pre-scaled q-weights
      const f32x4 bacc = {bias, bias, bias, bias};
      #pragma unroll
      for (int wv = 0; wv < 2; wv++){
        f32x4 acc = bacc;
        acc = MFMA16(A0[wv], w0, acc);
        acc = MFMA16(A1[wv], w1, acc);
        acc = MFMA16(A2[wv], w2, acc);
        if (sect == 0){
          #pragma unroll
          for (int r = 0; r < 4; r++){
            const float qv = PRE ? acc[r] : acc[r]*QSC;
            *(bf16*)(s_q + (wv*64 + row0 + r)*64 + d*2) = f2b(qv);
          }
        } else if (sect == 1){
          #pragma unroll
          for (int r = 0; r < 4; r++)
            *(bf16*)(s_k + (wv*64 + row0 + r)*64 + d*2) = f2b(acc[r]);
        } else {
          short4v pkv;
          #pragma unroll
          for (int r = 0; r < 4; r++) pkv[r] = f2s(acc[r]);
          *(short4v*)(s_vt + wv*4096 + d*128 + row0*2) = pkv;   // V^T, 4 consecutive tokens
        }
      }
    }
    __syncthreads();   // (3..) k, vt (cross-wave) ready

    // ---- SWAPPED scores S^T = mfma(K,Q): lane holds S[k=nt*16+quad*4+r][q=m0+l15]
    //      -> in-lane softmax over k -> quad-exchange shuffles -> PV A-frags (no P LDS)
    #pragma unroll
    for (int wv = 0; wv < 2; wv++){
      const short8 bq = *(const short8*)(s_q + (wv*64 + m0 + l15)*64 + quad*16);
      f32x4 st[4];
      #pragma unroll
      for (int nt = 0; nt < 4; nt++){
        f32x4 bb;
        if constexpr (PRE){
          const float4 b4 = *(const float4*)(btab + (h*64 + m0 + l15)*64 + nt*16 + quad*4);
          bb[0]=b4.x; bb[1]=b4.y; bb[2]=b4.z; bb[3]=b4.w;
        } else {
          const int q = m0 + l15, qi = q >> 3, qj = q & 7;
          #pragma unroll
          for (int r = 0; r < 4; r++){
            const int k = nt*16 + quad*4 + r, ki = k >> 3, kj = k & 7;
            bb[r] = rpb[((qi - ki + 7)*15 + (qj - kj + 7))*3 + h];
          }
        }
        const short8 ak = *(const short8*)(s_k + (wv*64 + nt*16 + l15)*64 + quad*16);
        st[nt] = MFMA16(ak, bq, bb);   // bias folded into C-input
      }
      // softmax over k for fixed q: exp (clamped, no max-sub), in-lane sum + 2 shfl
      float e[16];
      float tot = 0.f;
      #pragma unroll
      for (int nt = 0; nt < 4; nt++)
        #pragma unroll
        for (int r = 0; r < 4; r++){
          const float v = __expf(fminf(st[nt][r], 80.f));
          e[nt*4+r] = v; tot += v;
        }
      tot += __shfl_xor(tot, 16);
      tot += __shfl_xor(tot, 32);
      const float rs = 1.f / tot;
      uint pk[8];                      // pk[nt*2+hp] = bf16 pair (r=2hp, r=2hp+1)
      #pragma unroll
      for (int nt = 0; nt < 4; nt++){
        pk[nt*2+0] = pk2(e[nt*4+0]*rs, e[nt*4+1]*rs);
        pk[nt*2+1] = pk2(e[nt*4+2]*rs, e[nt*4+3]*rs);
      }
      // quad-exchange: target frag elem j -> k=s*32+quad*8+j held by lane (2(quad&1)+(j>=4))*16+l15,
      // reg nt'=2s+(quad>>1), pair hp=(j&3)>>1.  8 shfls/frag (half selected away).
      const int lane0 = (quad & 1)*32 + l15;
      const int lane1 = lane0 + 16;
      const bool hiq = quad >= 2;
      short8 pa[2];
      #pragma unroll
      for (int s = 0; s < 2; s++){
        const uint aA0 = __shfl(pk[4*s+0], lane0);
        const uint aA1 = __shfl(pk[4*s+1], lane0);
        const uint aB0 = __shfl(pk[4*s+2], lane0);
        const uint aB1 = __shfl(pk[4*s+3], lane0);
        const uint cA0 = __shfl(pk[4*s+0], lane1);
        const uint cA1 = __shfl(pk[4*s+1], lane1);
        const uint cB0 = __shfl(pk[4*s+2], lane1);
        const uint cB1 = __shfl(pk[4*s+3], lane1);
        uint4v u;
        u[0] = hiq ? aB0 : aA0;   // j=0,1
        u[1] = hiq ? aB1 : aA1;   // j=2,3
        u[2] = hiq ? cB0 : cA0;   // j=4,5
        u[3] = hiq ? cB1 : cA1;   // j=6,7
        pa[s] = __builtin_bit_cast(short8, u);
      }
      // PV : out[token=row0+r][d=ntv*16+l15] -> ao[:, h*32+d]
      #pragma unroll
      for (int ntv = 0; ntv < 2; ntv++){
        const char* vr = s_vt + wv*4096 + (ntv*16 + l15)*128 + quad*16;
        f32x4 acc = zac;
        acc = MFMA16(pa[0], *(const short8*)(vr), acc);       // tokens 0..31
        acc = MFMA16(pa[1], *(const short8*)(vr + 64), acc);  // tokens 32..63
        #pragma unroll
        for (int r = 0; r < 4; r++)
          *(bf16*)(s_ao + (wv*64 + row0 + r)*192 + (h*32 + ntv*16 + l15)*2) = f2b(acc[r]);
      }
    }
    __syncthreads();   // protect q/k/vt overwrite (next head) / A-region overwrite (LN2)
  }

  // ---------------- proj with FUSED LN2 epilogue -> LN2-out into A region ----
  {
    short8 B0[2], B1[2], B2[2];
    #pragma unroll
    for (int wv = 0; wv < 2; wv++){
      const char* bp = s_ao + (wv*64 + m0 + l15)*192 + quad*16;   // own-wave rows
      B0[wv] = *(const short8*)(bp);
      B1[wv] = *(const short8*)(bp + 64);
      B2[wv] = *(const short8*)(bp + 128);
    }
    float g6[6], b6[6];
    #pragma unroll
    for (int nt = 0; nt < 6; nt++){
      g6[nt] = n2g[nt*16 + l15];
      b6[nt] = n2b[nt*16 + l15];
    }
    float vals[2][6][4];
    #pragma unroll
    for (int nt = 0; nt < 6; nt++){
      const int wrow = nt*16 + l15;
      short8 w0, w1, w2;
      if constexpr (PRE){
        const bf16* wp = wP + wrow*96 + quad*8;
        w0 = *(const short8*)(wp);
        w1 = *(const short8*)(wp + 32);
        w2 = *(const short8*)(wp + 64);
      } else {
        const float* wp = projw + wrow*96 + quad*8;
        w0 = ldw8(wp); w1 = ldw8(wp + 32); w2 = ldw8(wp + 64);
      }
      const float bias = projb[wrow];
      const f32x4 bacc = {bias, bias, bias, bias};
      #pragma unroll
      for (int wv = 0; wv < 2; wv++){
        f32x4 acc = bacc;
        acc = MFMA16(B0[wv], w0, acc);
        acc = MFMA16(B1[wv], w1, acc);
        acc = MFMA16(B2[wv], w2, acc);
        #pragma unroll
        for (int r = 0; r < 4; r++) vals[wv][nt][r] = acc[r];
      }
    }
    // LN2 stats: row lives in the 16 l15-lanes of one quad (6 vals each)
    #pragma unroll
    for (int wv = 0; wv < 2; wv++){
      #pragma unroll
      for (int r = 0; r < 4; r++){
        float sm = 0.f, sq = 0.f;
        #pragma unroll
        for (int nt = 0; nt < 6; nt++){ const float v = vals[wv][nt][r]; sm += v; sq += v*v; }
        sm += __shfl_xor(sm, 1); sm += __shfl_xor(sm, 2);
        sm += __shfl_xor(sm, 4); sm += __shfl_xor(sm, 8);
        sq += __shfl_xor(sq, 1); sq += __shfl_xor(sq, 2);
        sq += __shfl_xor(sq, 4); sq += __shfl_xor(sq, 8);
        const float mu  = sm * (1.f/96.f);
        const float inv = rsqrtf(fmaxf(sq*(1.f/96.f) - mu*mu, 0.f) + EPS);
        char* ob = s_a + (wv*64 + row0 + r)*192;
        #pragma unroll
        for (int nt = 0; nt < 6; nt++)
          *(bf16*)(ob + (nt*16 + l15)*2) =
              f2b((vals[wv][nt][r] - mu) * inv * g6[nt] + b6[nt]);
      }
    }
  }
  // no barrier: LN2-out rows are wave-private; C-hoist below reads own rows

  // ---------------- fc1(+GELU) / fc2, half-split over HIDDEN; acc in regs ----
  {
    short8 C0[2], C1[2], C2[2];
    #pragma unroll
    for (int wv = 0; wv < 2; wv++){
      const char* cp = s_a + (wv*64 + m0 + l15)*192 + quad*16;
      C0[wv] = *(const short8*)(cp);
      C1[wv] = *(const short8*)(cp + 64);
      C2[wv] = *(const short8*)(cp + 128);
    }
    __syncthreads();   // all C-hoists done before s_at overwrites A region

    f32x4 acc2[2][6];
    #pragma unroll
    for (int nt = 0; nt < 6; nt++){
      const float bias = fc2b[nt*16 + l15];
      #pragma unroll
      for (int wv = 0; wv < 2; wv++){
        acc2[wv][nt][0] = bias; acc2[wv][nt][1] = bias;
        acc2[wv][nt][2] = bias; acc2[wv][nt][3] = bias;
      }
    }

    #pragma unroll
    for (int half = 0; half < 2; half++){
      // fc1 half: 96 hidden cols -> s_h [128][192B] (own-wave rows; no barrier)
      #pragma unroll
      for (int nt = 0; nt < 6; nt++){
        const int wrow = half*96 + nt*16 + l15;
        short8 w0, w1, w2;
        if constexpr (PRE){
          const bf16* wp = wF1 + wrow*96 + quad*8;
          w0 = *(const short8*)(wp);
          w1 = *(const short8*)(wp + 32);
          w2 = *(const short8*)(wp + 64);
        } else {
          const float* wp = fc1w + wrow*96 + quad*8;
          w0 = ldw8(wp); w1 = ldw8(wp + 32); w2 = ldw8(wp + 64);
        }
        const float bias = fc1b[wrow];
        const f32x4 bacc = {bias, bias, bias, bias};
        #pragma unroll
        for (int wv = 0; wv < 2; wv++){
          f32x4 acc = bacc;
          acc = MFMA16(C0[wv], w0, acc);
          acc = MFMA16(C1[wv], w1, acc);
          acc = MFMA16(C2[wv], w2, acc);
          #pragma unroll
          for (int r = 0; r < 4; r++){
            const float v = acc[r];
            // GELU via tanh identity: g = v - v/(e^{2y}+1), y = 0.7978845608*(v+0.044715 v^3)
            const float t = __expf(1.5957691216057308f * (v + 0.044715f*v*v*v));
            const float g = v - v * (1.f / (t + 1.f));
            *(bf16*)(s_h + (wv*64 + row0 + r)*192 + (nt*16 + l15)*2) = f2b(g);
          }
        }
      }
      // fc2 partial over this half's K=96 (own-wave rows of s_h; compiler waits)
      short8 F0[2], F1[2], F2[2];
      #pragma unroll
      for (int wv = 0; wv < 2; wv++){
        const char* fp = s_h + (wv*64 + m0 + l15)*192 + quad*16;
        F0[wv] = *(const short8*)(fp);
        F1[wv] = *(const short8*)(fp + 64);
        F2[wv] = *(const short8*)(fp + 128);
      }
      #pragma unroll
      for (int nt = 0; nt < 6; nt++){
        const int wrow = nt*16 + l15;
        short8 w0, w1, w2;
        if constexpr (PRE){
          const bf16* wp = wF2 + wrow*192 + half*96 + quad*8;
          w0 = *(const short8*)(wp);
          w1 = *(const short8*)(wp + 32);
          w2 = *(const short8*)(wp + 64);
        } else {
          const float* wp = fc2w + wrow*192 + half*96 + quad*8;
          w0 = ldw8(wp); w1 = ldw8(wp + 32); w2 = ldw8(wp + 64);
        }
        #pragma unroll
        for (int wv = 0; wv < 2; wv++){
          acc2[wv][nt] = MFMA16(F0[wv], w0, acc2[wv][nt]);
          acc2[wv][nt] = MFMA16(F1[wv], w1, acc2[wv][nt]);
          acc2[wv][nt] = MFMA16(F2[wv], w2, acc2[wv][nt]);
        }
      }
    }

    // write fc2 out transposed: s_at[c][token]
    #pragma unroll
    for (int nt = 0; nt < 6; nt++){
      const int wrow = nt*16 + l15;
      #pragma unroll
      for (int wv = 0; wv < 2; wv++){
        short4v pkv;
        #pragma unroll
        for (int r = 0; r < 4; r++) pkv[r] = f2s(acc2[wv][nt][r]);
        *(short4v*)(s_at + wrow*256 + (wv*64 + row0)*2) = pkv;
      }
    }
  }
  __syncthreads();   // s_at cross-wave

  // ---------------- writeout: re-read x, fp32 residual add, window merge ----
  #pragma unroll
  for (int it = 0; it < 12; it++){
    const int idx4 = it*256 + tid;
    const int c = idx4 >> 5, r = idx4 & 31;
    const int irow = r >> 2, j0 = (r & 3) * 4;
    const int t0 = (j0 >> 3)*64 + irow*8 + (j0 & 7);
    const short4v pv = *(const short4v*)(s_at + c*256 + t0*2);
    const size_t g = base + (size_t)c*65536 + irow*256 + j0;
    const float4 xv = *(const float4*)(x + g);
    float4 ov;
    ov.x = xv.x + s2f(pv[0]);
    ov.y = xv.y + s2f(pv[1]);
    ov.z = xv.z + s2f(pv[2]);
    ov.w = xv.w + s2f(pv[3]);
    *(float4*)(out + g) = ov;
  }
}

extern "C" void kernel_launch(void* const* d_in, const int* in_sizes, int n_in,
                              void* d_out, int out_size, void* d_ws, size_t ws_size,
                              hipStream_t stream) {
  const float* x     = (const float*)d_in[0];
  const float* qkvw  = (const float*)d_in[1];
  const float* qkvb  = (const float*)d_in[2];
  const float* projw = (const float*)d_in[3];
  const float* projb = (const float*)d_in[4];
  const float* rpb   = (const float*)d_in[5];
  const float* n1g   = (const float*)d_in[6];
  const float* n1b   = (const float*)d_in[7];
  const float* n2g   = (const float*)d_in[8];
  const float* n2b   = (const float*)d_in[9];
  const float* fc1w  = (const float*)d_in[10];
  const float* fc1b  = (const float*)d_in[11];
  const float* fc2w  = (const float*)d_in[12];
  const float* fc2b  = (const float*)d_in[13];
  float* out = (float*)d_out;

  if (ws_size >= WS_NEEDED && d_ws != nullptr) {
    bf16*  wbf  = (bf16*)d_ws;
    float* btab = (float*)((char*)d_ws + BTAB_BYTE_OFF);
    init_ws_kernel<<<dim3(288), dim3(256), 0, stream>>>(
        qkvw, projw, fc1w, fc2w, rpb, wbf, btab);
    swin_block_kernel<true><<<dim3(4096), dim3(TPB), 0, stream>>>(
        x, qkvw, qkvb, projw, projb, rpb,
        n1g, n1b, n2g, n2b, fc1w, fc1b, fc2w, fc2b, out, wbf, btab);
  } else {
    swin_block_kernel<false><<<dim3(4096), dim3(TPB), 0, stream>>>(
        x, qkvw, qkvb, projw, projb, rpb,
        n1g, n1b, n2g, n2b, fc1w, fc1b, fc2w, fc2b, out,
        (const bf16*)nullptr, (const float*)nullptr);
  }
}